// Round 1
// baseline (161.453 us; speedup 1.0000x reference)
//
#include <hip/hip_runtime.h>

// PointPillarScatter: out[b][c][y][x] = pf[b][p][c] where coords[b][p] = (b,0,y,x), else 0.
// B=8, P=20000, C=64, NX=432, NY=496. Output (8,64,496,432) fp32.
//
// Strategy: invert the scatter into a gather.
//   K1: map[b][cell] = -1                                   (6.9 MB ws fill)
//   K2: map[b][y*NX+x] = p   for each pillar                (160k coalesced writes)
//   K3: out[b][c][cell] = map>=0 ? pf[b][p][c] : 0          (coalesced float4 output pass)

#define BB    8
#define PP    20000
#define CC    64
#define NXX   432
#define NYY   496
#define NCELL (NXX * NYY)   /* 214272 */
#define NCELL4 (NCELL / 4)  /* 53568  */

__global__ void ppsc_init_map(int* __restrict__ map, int n4) {
    int t = blockIdx.x * blockDim.x + threadIdx.x;
    if (t < n4) ((int4*)map)[t] = make_int4(-1, -1, -1, -1);
}

__global__ void ppsc_scatter_map(const int* __restrict__ coords, int* __restrict__ map) {
    int t = blockIdx.x * blockDim.x + threadIdx.x;  // one thread per (b,p)
    if (t >= BB * PP) return;
    int b = t / PP;
    int p = t - b * PP;
    const int4 c4 = ((const int4*)coords)[t];       // [b, z, y, x] as int32
    int y = c4.z, x = c4.w;
    if ((unsigned)y < (unsigned)NYY && (unsigned)x < (unsigned)NXX)
        map[b * NCELL + y * NXX + x] = p;
}

__global__ void ppsc_gather(const float* __restrict__ pf,
                            const int* __restrict__ map,
                            float* __restrict__ out) {
    int t = blockIdx.x * blockDim.x + threadIdx.x;  // one thread per 4 output cells
    if (t >= BB * CC * NCELL4) return;
    int i4 = t % NCELL4;
    int bc = t / NCELL4;        // b*CC + c
    int c  = bc % CC;
    int b  = bc / CC;

    int4 m = ((const int4*)(map + b * NCELL))[i4];
    const float* pfb = pf + (size_t)b * PP * CC + c;
    float4 v;
    v.x = (m.x >= 0) ? pfb[(size_t)m.x * CC] : 0.f;
    v.y = (m.y >= 0) ? pfb[(size_t)m.y * CC] : 0.f;
    v.z = (m.z >= 0) ? pfb[(size_t)m.z * CC] : 0.f;
    v.w = (m.w >= 0) ? pfb[(size_t)m.w * CC] : 0.f;
    ((float4*)(out + (size_t)bc * NCELL))[i4] = v;
}

// ---- fallback path (ws too small): zero output + direct scatter ----
__global__ void ppsc_zero(float* __restrict__ out, int n4) {
    int t = blockIdx.x * blockDim.x + threadIdx.x;
    if (t < n4) ((float4*)out)[t] = make_float4(0.f, 0.f, 0.f, 0.f);
}

__global__ void ppsc_direct_scatter(const float* __restrict__ pf,
                                    const int* __restrict__ coords,
                                    float* __restrict__ out) {
    int t = blockIdx.x * blockDim.x + threadIdx.x;  // one thread per (b,p,c)
    if (t >= BB * PP * CC) return;
    int c  = t % CC;
    int bp = t / CC;
    int b  = bp / PP;
    const int* cd = coords + (size_t)bp * 4;
    int y = cd[2], x = cd[3];
    if ((unsigned)y < (unsigned)NYY && (unsigned)x < (unsigned)NXX)
        out[((size_t)(b * CC + c)) * NCELL + (size_t)y * NXX + x] = pf[(size_t)bp * CC + c];
}

extern "C" void kernel_launch(void* const* d_in, const int* in_sizes, int n_in,
                              void* d_out, int out_size, void* d_ws, size_t ws_size,
                              hipStream_t stream) {
    const float* pf     = (const float*)d_in[0];
    const int*   coords = (const int*)d_in[1];
    float*       out    = (float*)d_out;

    const size_t map_bytes = (size_t)BB * NCELL * sizeof(int);

    if (ws_size >= map_bytes) {
        int* map = (int*)d_ws;

        int n4_map = (BB * NCELL) / 4;  // 428544
        ppsc_init_map<<<(n4_map + 255) / 256, 256, 0, stream>>>(map, n4_map);

        int npil = BB * PP;             // 160000
        ppsc_scatter_map<<<(npil + 255) / 256, 256, 0, stream>>>(coords, map);

        int ngth = BB * CC * NCELL4;    // 27,426,816
        ppsc_gather<<<(ngth + 255) / 256, 256, 0, stream>>>(pf, map, out);
    } else {
        int n4_out = out_size / 4;
        ppsc_zero<<<(n4_out + 255) / 256, 256, 0, stream>>>(out, n4_out);

        int nsc = BB * PP * CC;         // 10,240,000
        ppsc_direct_scatter<<<(nsc + 255) / 256, 256, 0, stream>>>(pf, coords, out);
    }
}

// Round 3
// 121.729 us; speedup vs baseline: 1.3263x; 1.3263x over previous
//
#include <hip/hip_runtime.h>

// PointPillarScatter: out[b][c][y][x] = pf[b][p][c] where coords[b][p] = (b,0,y,x), else 0.
// B=8, P=20000, C=64, NX=432, NY=496. Output (8,64,496,432) fp32.
//
// Gather formulation:
//   K1: map[b][cell] = -1
//   K2: map[b][y*NX+x] = p
//   K3: each thread: 4 cells x 4 channels. int4 map read serves 4 planes;
//       scattered pf reads are float4 (4 contiguous channels of one pillar);
//       4x4 register transpose; 4 coalesced nontemporal 16B stores.

#define BB    8
#define PP    20000
#define CC    64
#define NXX   432
#define NYY   496
#define NCELL (NXX * NYY)   /* 214272 */
#define NCELL4 (NCELL / 4)  /* 53568  */

typedef float f32x4 __attribute__((ext_vector_type(4)));

__global__ void ppsc_init_map(int* __restrict__ map, int n4) {
    int t = blockIdx.x * blockDim.x + threadIdx.x;
    if (t < n4) ((int4*)map)[t] = make_int4(-1, -1, -1, -1);
}

__global__ void ppsc_scatter_map(const int* __restrict__ coords, int* __restrict__ map) {
    int t = blockIdx.x * blockDim.x + threadIdx.x;  // one thread per (b,p)
    if (t >= BB * PP) return;
    int b = t / PP;
    int p = t - b * PP;
    const int4 c4 = ((const int4*)coords)[t];       // [b, z, y, x] as int32
    int y = c4.z, x = c4.w;
    if ((unsigned)y < (unsigned)NYY && (unsigned)x < (unsigned)NXX)
        map[b * NCELL + y * NXX + x] = p;
}

// thread t -> (b, cq, i4): b batch, cq channel-quad (0..15), i4 cell-quad (0..NCELL4-1)
__global__ void __launch_bounds__(256) ppsc_gather4(const float* __restrict__ pf,
                                                    const int* __restrict__ map,
                                                    float* __restrict__ out) {
    int t = blockIdx.x * blockDim.x + threadIdx.x;
    if (t >= BB * 16 * NCELL4) return;
    int i4 = t % NCELL4;
    int bq = t / NCELL4;
    int cq = bq % 16;
    int b  = bq / 16;

    int4 m = ((const int4*)(map + b * NCELL))[i4];
    const float* pfb = pf + (size_t)b * PP * CC + cq * 4;

    f32x4 o0 = (f32x4)0.f, o1 = (f32x4)0.f, o2 = (f32x4)0.f, o3 = (f32x4)0.f;

    if (m.x >= 0) { f32x4 f = *(const f32x4*)(pfb + (size_t)m.x * CC);
                    o0.x = f.x; o1.x = f.y; o2.x = f.z; o3.x = f.w; }
    if (m.y >= 0) { f32x4 f = *(const f32x4*)(pfb + (size_t)m.y * CC);
                    o0.y = f.x; o1.y = f.y; o2.y = f.z; o3.y = f.w; }
    if (m.z >= 0) { f32x4 f = *(const f32x4*)(pfb + (size_t)m.z * CC);
                    o0.z = f.x; o1.z = f.y; o2.z = f.z; o3.z = f.w; }
    if (m.w >= 0) { f32x4 f = *(const f32x4*)(pfb + (size_t)m.w * CC);
                    o0.w = f.x; o1.w = f.y; o2.w = f.z; o3.w = f.w; }

    float* ob = out + ((size_t)(b * CC + cq * 4)) * NCELL;
    __builtin_nontemporal_store(o0, ((f32x4*)ob) + i4);
    __builtin_nontemporal_store(o1, ((f32x4*)(ob + (size_t)NCELL)) + i4);
    __builtin_nontemporal_store(o2, ((f32x4*)(ob + 2 * (size_t)NCELL)) + i4);
    __builtin_nontemporal_store(o3, ((f32x4*)(ob + 3 * (size_t)NCELL)) + i4);
}

// ---- fallback path (ws too small): zero output + direct scatter ----
__global__ void ppsc_zero(float* __restrict__ out, int n4) {
    int t = blockIdx.x * blockDim.x + threadIdx.x;
    if (t < n4) ((float4*)out)[t] = make_float4(0.f, 0.f, 0.f, 0.f);
}

__global__ void ppsc_direct_scatter(const float* __restrict__ pf,
                                    const int* __restrict__ coords,
                                    float* __restrict__ out) {
    int t = blockIdx.x * blockDim.x + threadIdx.x;  // one thread per (b,p,c)
    if (t >= BB * PP * CC) return;
    int c  = t % CC;
    int bp = t / CC;
    int b  = bp / PP;
    const int* cd = coords + (size_t)bp * 4;
    int y = cd[2], x = cd[3];
    if ((unsigned)y < (unsigned)NYY && (unsigned)x < (unsigned)NXX)
        out[((size_t)(b * CC + c)) * NCELL + (size_t)y * NXX + x] = pf[(size_t)bp * CC + c];
}

extern "C" void kernel_launch(void* const* d_in, const int* in_sizes, int n_in,
                              void* d_out, int out_size, void* d_ws, size_t ws_size,
                              hipStream_t stream) {
    const float* pf     = (const float*)d_in[0];
    const int*   coords = (const int*)d_in[1];
    float*       out    = (float*)d_out;

    const size_t map_bytes = (size_t)BB * NCELL * sizeof(int);

    if (ws_size >= map_bytes) {
        int* map = (int*)d_ws;

        int n4_map = (BB * NCELL) / 4;       // 428544
        ppsc_init_map<<<(n4_map + 255) / 256, 256, 0, stream>>>(map, n4_map);

        int npil = BB * PP;                  // 160000
        ppsc_scatter_map<<<(npil + 255) / 256, 256, 0, stream>>>(coords, map);

        int ngth = BB * 16 * NCELL4;         // 6,856,704 threads
        ppsc_gather4<<<(ngth + 255) / 256, 256, 0, stream>>>(pf, map, out);
    } else {
        int n4_out = out_size / 4;
        ppsc_zero<<<(n4_out + 255) / 256, 256, 0, stream>>>(out, n4_out);

        int nsc = BB * PP * CC;              // 10,240,000
        ppsc_direct_scatter<<<(nsc + 255) / 256, 256, 0, stream>>>(pf, coords, out);
    }
}

// Round 4
// 100.429 us; speedup vs baseline: 1.6076x; 1.2121x over previous
//
#include <hip/hip_runtime.h>

// PointPillarScatter: out[b][c][y][x] = pf[b][p][c] where coords[b][p] = (b,0,y,x), else 0.
// B=8, P=20000, C=64, NX=432, NY=496. Output (8,64,496,432) fp32.
//
// Gather formulation:
//   K1: map[b][cell] = -1
//   K2: map[b][y*NX+x] = p
//   K3: one thread per (b, 4-cell group); loops all 16 channel-quads.
//       Map int4 read ONCE per thread (was x16). Pillar rows streamed as
//       float4 per quad; 4x4 register transpose; nontemporal coalesced stores.
//       Bijective chunked XCD swizzle: ~209 blocks/batch, 8 XCDs, 8 batches ->
//       each XCD's L2 caches one batch's pf slice (5.1 MB) + map (0.9 MB).

#define BB    8
#define PP    20000
#define CC    64
#define NXX   432
#define NYY   496
#define NCELL (NXX * NYY)   /* 214272 */
#define NCELL4 (NCELL / 4)  /* 53568  */

#define GATHER_BLK   256
#define GATHER_NWG   ((BB * NCELL4) / GATHER_BLK)  /* 428544/256 = 1674 exactly */
#define NXCD         8
#define SWZ_Q        (GATHER_NWG / NXCD)           /* 209 */
#define SWZ_R        (GATHER_NWG % NXCD)           /* 2   */

typedef float f32x4 __attribute__((ext_vector_type(4)));

__global__ void ppsc_init_map(int* __restrict__ map, int n4) {
    int t = blockIdx.x * blockDim.x + threadIdx.x;
    if (t < n4) ((int4*)map)[t] = make_int4(-1, -1, -1, -1);
}

__global__ void ppsc_scatter_map(const int* __restrict__ coords, int* __restrict__ map) {
    int t = blockIdx.x * blockDim.x + threadIdx.x;  // one thread per (b,p)
    if (t >= BB * PP) return;
    int b = t / PP;
    int p = t - b * PP;
    const int4 c4 = ((const int4*)coords)[t];       // [b, z, y, x] as int32
    int y = c4.z, x = c4.w;
    if ((unsigned)y < (unsigned)NYY && (unsigned)x < (unsigned)NXX)
        map[b * NCELL + y * NXX + x] = p;
}

// one thread per (b, cell-quad); all 64 channels.
__global__ void __launch_bounds__(GATHER_BLK) ppsc_gather_all(const float* __restrict__ pf,
                                                              const int* __restrict__ map,
                                                              float* __restrict__ out) {
    // bijective chunked XCD swizzle (m204): consecutive hardware bids round-robin
    // across XCDs; remap so each XCD owns a contiguous chunk of logical work.
    int bid = blockIdx.x;
    int xcd = bid % NXCD;
    int idx = bid / NXCD;
    int wg  = (xcd < SWZ_R ? xcd * (SWZ_Q + 1) : SWZ_R * (SWZ_Q + 1) + (xcd - SWZ_R) * SWZ_Q) + idx;

    int t = wg * GATHER_BLK + threadIdx.x;
    if (t >= BB * NCELL4) return;
    int i4 = t % NCELL4;
    int b  = t / NCELL4;

    int4 m = ((const int4*)(map + b * NCELL))[i4];
    const float* base = pf + (size_t)b * PP * CC;
    const float* p0 = base + (size_t)m.x * CC;
    const float* p1 = base + (size_t)m.y * CC;
    const float* p2 = base + (size_t)m.z * CC;
    const float* p3 = base + (size_t)m.w * CC;

    float* ob = out + (size_t)b * CC * NCELL + (size_t)i4 * 4;

#pragma unroll
    for (int cq = 0; cq < 16; ++cq) {
        f32x4 o0 = (f32x4)0.f, o1 = (f32x4)0.f, o2 = (f32x4)0.f, o3 = (f32x4)0.f;
        if (m.x >= 0) { f32x4 f = *(const f32x4*)(p0 + cq * 4);
                        o0.x = f.x; o1.x = f.y; o2.x = f.z; o3.x = f.w; }
        if (m.y >= 0) { f32x4 f = *(const f32x4*)(p1 + cq * 4);
                        o0.y = f.x; o1.y = f.y; o2.y = f.z; o3.y = f.w; }
        if (m.z >= 0) { f32x4 f = *(const f32x4*)(p2 + cq * 4);
                        o0.z = f.x; o1.z = f.y; o2.z = f.z; o3.z = f.w; }
        if (m.w >= 0) { f32x4 f = *(const f32x4*)(p3 + cq * 4);
                        o0.w = f.x; o1.w = f.y; o2.w = f.z; o3.w = f.w; }
        float* op = ob + (size_t)(cq * 4) * NCELL;
        __builtin_nontemporal_store(o0, (f32x4*)op);
        __builtin_nontemporal_store(o1, (f32x4*)(op + (size_t)NCELL));
        __builtin_nontemporal_store(o2, (f32x4*)(op + 2 * (size_t)NCELL));
        __builtin_nontemporal_store(o3, (f32x4*)(op + 3 * (size_t)NCELL));
    }
}

// ---- fallback path (ws too small): zero output + direct scatter ----
__global__ void ppsc_zero(float* __restrict__ out, int n4) {
    int t = blockIdx.x * blockDim.x + threadIdx.x;
    if (t < n4) ((float4*)out)[t] = make_float4(0.f, 0.f, 0.f, 0.f);
}

__global__ void ppsc_direct_scatter(const float* __restrict__ pf,
                                    const int* __restrict__ coords,
                                    float* __restrict__ out) {
    int t = blockIdx.x * blockDim.x + threadIdx.x;  // one thread per (b,p,c)
    if (t >= BB * PP * CC) return;
    int c  = t % CC;
    int bp = t / CC;
    int b  = bp / PP;
    const int* cd = coords + (size_t)bp * 4;
    int y = cd[2], x = cd[3];
    if ((unsigned)y < (unsigned)NYY && (unsigned)x < (unsigned)NXX)
        out[((size_t)(b * CC + c)) * NCELL + (size_t)y * NXX + x] = pf[(size_t)bp * CC + c];
}

extern "C" void kernel_launch(void* const* d_in, const int* in_sizes, int n_in,
                              void* d_out, int out_size, void* d_ws, size_t ws_size,
                              hipStream_t stream) {
    const float* pf     = (const float*)d_in[0];
    const int*   coords = (const int*)d_in[1];
    float*       out    = (float*)d_out;

    const size_t map_bytes = (size_t)BB * NCELL * sizeof(int);

    if (ws_size >= map_bytes) {
        int* map = (int*)d_ws;

        int n4_map = (BB * NCELL) / 4;       // 428544
        ppsc_init_map<<<(n4_map + 255) / 256, 256, 0, stream>>>(map, n4_map);

        int npil = BB * PP;                  // 160000
        ppsc_scatter_map<<<(npil + 255) / 256, 256, 0, stream>>>(coords, map);

        ppsc_gather_all<<<GATHER_NWG, GATHER_BLK, 0, stream>>>(pf, map, out);
    } else {
        int n4_out = out_size / 4;
        ppsc_zero<<<(n4_out + 255) / 256, 256, 0, stream>>>(out, n4_out);

        int nsc = BB * PP * CC;              // 10,240,000
        ppsc_direct_scatter<<<(nsc + 255) / 256, 256, 0, stream>>>(pf, coords, out);
    }
}

// Round 5
// 97.048 us; speedup vs baseline: 1.6636x; 1.0348x over previous
//
#include <hip/hip_runtime.h>

// PointPillarScatter: out[b][c][y][x] = pf[b][p][c] where coords[b][p] = (b,0,y,x), else 0.
// B=8, P=20000, C=64, NX=432, NY=496. Output (8,64,496,432) fp32.
//
// Gather formulation:
//   K1: map16[b][cell] = 0xFFFF                 (ushort map: 3.4 MB)
//   K2: map16[b][y*NX+x] = p                    (p < 20000 < 0xFFFF)
//   K3: one thread per (b, 4-cell group); loops all 16 channel-quads.
//       64-thread blocks: 6696 blocks = 26.2/CU (tail imbalance 3.7%, was 14%).
//       6696 = 8 XCDs x 837, and 837 blocks == exactly one batch ->
//       chunked swizzle gives each XCD exactly one batch's pf+map.

#define BB    8
#define PP    20000
#define CC    64
#define NXX   432
#define NYY   496
#define NCELL (NXX * NYY)   /* 214272 */
#define NCELL4 (NCELL / 4)  /* 53568  */

#define GBLK   64
#define GNWG   ((BB * NCELL4) / GBLK)  /* 428544/64 = 6696 exactly */
#define NXCD   8
#define CHUNK  (GNWG / NXCD)           /* 837: exactly one batch per XCD */

typedef float f32x4 __attribute__((ext_vector_type(4)));
typedef unsigned short u16;
typedef u16 u16x4 __attribute__((ext_vector_type(4)));

__global__ void ppsc_init_map(int* __restrict__ map16_as_int, int n4) {
    int t = blockIdx.x * blockDim.x + threadIdx.x;
    if (t < n4) ((int4*)map16_as_int)[t] = make_int4(-1, -1, -1, -1);  // all 0xFFFF
}

__global__ void ppsc_scatter_map(const int* __restrict__ coords, u16* __restrict__ map16) {
    int t = blockIdx.x * blockDim.x + threadIdx.x;  // one thread per (b,p)
    if (t >= BB * PP) return;
    int b = t / PP;
    int p = t - b * PP;
    const int4 c4 = ((const int4*)coords)[t];       // [b, z, y, x] as int32
    int y = c4.z, x = c4.w;
    if ((unsigned)y < (unsigned)NYY && (unsigned)x < (unsigned)NXX)
        map16[(size_t)b * NCELL + y * NXX + x] = (u16)p;
}

// one thread per (b, cell-quad); all 64 channels.
__global__ void __launch_bounds__(GBLK) ppsc_gather_all(const float* __restrict__ pf,
                                                        const u16* __restrict__ map16,
                                                        float* __restrict__ out) {
    // chunked XCD swizzle: hardware bids round-robin XCDs; remap so XCD k owns
    // contiguous blocks [k*CHUNK, (k+1)*CHUNK) == exactly batch k.
    int bid = blockIdx.x;
    int wg  = (bid % NXCD) * CHUNK + bid / NXCD;

    int t  = wg * GBLK + threadIdx.x;
    int i4 = t % NCELL4;
    int b  = t / NCELL4;

    u16x4 m = ((const u16x4*)(map16 + (size_t)b * NCELL))[i4];
    const float* base = pf + (size_t)b * PP * CC;
    const float* p0 = base + (size_t)m.x * CC;
    const float* p1 = base + (size_t)m.y * CC;
    const float* p2 = base + (size_t)m.z * CC;
    const float* p3 = base + (size_t)m.w * CC;
    bool v0 = (m.x != 0xFFFFu), v1 = (m.y != 0xFFFFu),
         v2 = (m.z != 0xFFFFu), v3 = (m.w != 0xFFFFu);

    float* ob = out + (size_t)b * CC * NCELL + (size_t)i4 * 4;

#pragma unroll
    for (int cq = 0; cq < 16; ++cq) {
        f32x4 o0 = (f32x4)0.f, o1 = (f32x4)0.f, o2 = (f32x4)0.f, o3 = (f32x4)0.f;
        if (v0) { f32x4 f = *(const f32x4*)(p0 + cq * 4);
                  o0.x = f.x; o1.x = f.y; o2.x = f.z; o3.x = f.w; }
        if (v1) { f32x4 f = *(const f32x4*)(p1 + cq * 4);
                  o0.y = f.x; o1.y = f.y; o2.y = f.z; o3.y = f.w; }
        if (v2) { f32x4 f = *(const f32x4*)(p2 + cq * 4);
                  o0.z = f.x; o1.z = f.y; o2.z = f.z; o3.z = f.w; }
        if (v3) { f32x4 f = *(const f32x4*)(p3 + cq * 4);
                  o0.w = f.x; o1.w = f.y; o2.w = f.z; o3.w = f.w; }
        float* op = ob + (size_t)(cq * 4) * NCELL;
        __builtin_nontemporal_store(o0, (f32x4*)op);
        __builtin_nontemporal_store(o1, (f32x4*)(op + (size_t)NCELL));
        __builtin_nontemporal_store(o2, (f32x4*)(op + 2 * (size_t)NCELL));
        __builtin_nontemporal_store(o3, (f32x4*)(op + 3 * (size_t)NCELL));
    }
}

// ---- fallback path (ws too small): zero output + direct scatter ----
__global__ void ppsc_zero(float* __restrict__ out, int n4) {
    int t = blockIdx.x * blockDim.x + threadIdx.x;
    if (t < n4) ((float4*)out)[t] = make_float4(0.f, 0.f, 0.f, 0.f);
}

__global__ void ppsc_direct_scatter(const float* __restrict__ pf,
                                    const int* __restrict__ coords,
                                    float* __restrict__ out) {
    int t = blockIdx.x * blockDim.x + threadIdx.x;  // one thread per (b,p,c)
    if (t >= BB * PP * CC) return;
    int c  = t % CC;
    int bp = t / CC;
    int b  = bp / PP;
    const int* cd = coords + (size_t)bp * 4;
    int y = cd[2], x = cd[3];
    if ((unsigned)y < (unsigned)NYY && (unsigned)x < (unsigned)NXX)
        out[((size_t)(b * CC + c)) * NCELL + (size_t)y * NXX + x] = pf[(size_t)bp * CC + c];
}

extern "C" void kernel_launch(void* const* d_in, const int* in_sizes, int n_in,
                              void* d_out, int out_size, void* d_ws, size_t ws_size,
                              hipStream_t stream) {
    const float* pf     = (const float*)d_in[0];
    const int*   coords = (const int*)d_in[1];
    float*       out    = (float*)d_out;

    const size_t map_bytes = (size_t)BB * NCELL * sizeof(u16);  // 3.43 MB

    if (ws_size >= map_bytes) {
        u16* map16 = (u16*)d_ws;

        int n4_map = (int)(map_bytes / 16);  // 214272 int4 writes
        ppsc_init_map<<<(n4_map + 255) / 256, 256, 0, stream>>>((int*)map16, n4_map);

        int npil = BB * PP;                  // 160000
        ppsc_scatter_map<<<(npil + 255) / 256, 256, 0, stream>>>(coords, map16);

        ppsc_gather_all<<<GNWG, GBLK, 0, stream>>>(pf, map16, out);
    } else {
        int n4_out = out_size / 4;
        ppsc_zero<<<(n4_out + 255) / 256, 256, 0, stream>>>(out, n4_out);

        int nsc = BB * PP * CC;              // 10,240,000
        ppsc_direct_scatter<<<(nsc + 255) / 256, 256, 0, stream>>>(pf, coords, out);
    }
}